// Round 7
// baseline (1605.425 us; speedup 1.0000x reference)
//
#include <hip/hip_runtime.h>
#include <cstdint>
#include <cstddef>

// Persistent-kernel seq2seq LSTM (H=1024, 2 layers, T=64+64, V=32000):
//   Phase A: gih[t] = x_t @ Wih0.T + bih0 + bhh0 (enc+dec; teacher forcing =>
//            all decoder inputs known up front)
//   Phase B: recurrence with ALL recurrent weights in registers (192 f32/thread
//            across 65536 threads = 50 MB/phase), pipelined L0(t=r) || L1(t=r-1),
//            1 grid barrier/round (131 total). h-exchange uses AGENT-SCOPE
//            RELAXED ATOMICS (sc0 sc1: store-through to LLC, load-bypass of
//            stale L1/L2) so the steady-state barrier needs NO cache fences.
//   Phase C: logits = relu(dec_h) @ out_W.T + out_b; outW LDS-tiled 32 rows/chunk,
//            activations stored TRANSPOSED [k/4][t][4] so x-loads coalesce.
// Barrier: two-level arrival tree (8 group counters on separate cachelines ->
// root -> flag). Full-fence variant only where bulk normal stores cross wgs
// (post-Phase-A: gih; end-of-Phase-B: dechT).
// wave <-> hidden unit; lanes 0-15/16-31/32-47/48-63 = gates i/f/g/o; cell state
// lives in registers (lane-replicated).

#define NH   1024
#define NG   4096
#define NT   64
#define NV   32000
#define NWG  256
#define NTHR 256

struct SeqParams {
  const int *src, *tgt;
  const float *emb_src, *emb_tgt;
  const float *eWih0, *eWhh0, *ebih0, *ebhh0;
  const float *eWih1, *eWhh1, *ebih1, *ebhh1;
  const float *dWih0, *dWhh0, *dbih0, *dbhh0;
  const float *dWih1, *dWhh1, *dbih1, *dbhh1;
  const float *outW, *outb;
  float *out;
  unsigned *cnt;      // root arrival counter (own cacheline)
  unsigned *flag;     // release flag (own cacheline)
  unsigned *gcnt;     // 8 group counters, 128B apart
  float *h0b, *h1b, *gihE, *gihD, *dechT;
};

__device__ __forceinline__ float sigf(float x) { return 1.f / (1.f + expf(-x)); }

// Two-level grid barrier, round-numbered, monotone counters (no reset).
// FENCED=true: release __threadfence (wbl2: pushes this XCD's dirty L2 lines
// to LLC) before arrival, acquire __threadfence (inv L1/L2) after release —
// needed when bulk NORMAL stores cross wg boundaries at this barrier.
// FENCED=false: steady-state Phase B. The h-exchange data travels as
// agent-scope relaxed atomics (sc0 sc1 per-access): stores are through to LLC
// and complete (vmcnt) before the pre-barrier __syncthreads lets thread0
// arrive; loads bypass stale caches. The gcnt->cnt->flag chain is ISA-ordered
// (vmcnt + control dependency). Bounded spin: co-residency failure = fast
// wrong answer, not a harness-killing hang.
template <bool FENCED>
__device__ __forceinline__ void gbar(const SeqParams& p, unsigned round) {
  __syncthreads();
  if (threadIdx.x == 0) {
    if (FENCED) __threadfence();
    unsigned* gc = p.gcnt + ((blockIdx.x >> 5) << 5);   // group counter, 128B apart
    unsigned gprev = __hip_atomic_fetch_add(gc, 1u, __ATOMIC_RELAXED,
                                            __HIP_MEMORY_SCOPE_AGENT);
    bool released = false;
    if (gprev == round * 32u - 1u) {                    // group leader (32/round)
      unsigned rprev = __hip_atomic_fetch_add(p.cnt, 1u, __ATOMIC_RELAXED,
                                              __HIP_MEMORY_SCOPE_AGENT);
      if (rprev == round * 8u - 1u) {                   // final arriver: publish
        __hip_atomic_store(p.flag, round, __ATOMIC_RELAXED, __HIP_MEMORY_SCOPE_AGENT);
        released = true;
      }
    }
    if (!released) {
      for (unsigned it = 0; it < 8000000u; ++it) {      // ~0.5s cap
        if (__hip_atomic_load(p.flag, __ATOMIC_RELAXED, __HIP_MEMORY_SCOPE_AGENT)
            >= round) break;
        __builtin_amdgcn_s_sleep(1);                    // ~64cy release detect
      }
    }
    if (FENCED) __threadfence();
  }
  __syncthreads();
}

// Lane c16 of a 16-lane gate group loads its 64-float slice of a 1024-float row:
// float4s {c16 + 16*i}. From global: 256B contiguous per instruction per group.
// From LDS: ds_read_b128, 2-way bank aliasing (free per m136).
__device__ __forceinline__ void load_row64(const float* base, float* dst, int c16) {
  const float4* s = (const float4*)base + c16;
  #pragma unroll
  for (int i = 0; i < 16; ++i) {
    float4 v = s[16*i];
    dst[4*i+0]=v.x; dst[4*i+1]=v.y; dst[4*i+2]=v.z; dst[4*i+3]=v.w;
  }
}

__global__ __launch_bounds__(NTHR, 1)
void seq2seq_kernel(SeqParams p) {
  const int tid = threadIdx.x;
  const int wg  = blockIdx.x;
  const int gt  = wg * NTHR + tid;
  const int u   = gt >> 6;        // wave id == hidden unit 0..1023
  const int l   = gt & 63;        // lane
  const int gi  = l >> 4;         // gate 0..3 (i,f,g,o)
  const int c16 = l & 15;         // position within gate group
  const int rowg = gi * NH + u;   // gate row in the 4096-row gate matrix
  unsigned rnd = 0;

  __shared__ float Wl[32 * NH];   // 128 KB. Phase C: 32-row outW tile (1 wg/CU by
  float* hst0 = Wl;               //   design, 160KB LDS). Phase B: first 8 KB =
  float* hst1 = Wl + NH;          //   h0_prev / h1_prev staging.

  // ------------- Phase A: gih[t][row] = x_t . Wih0[row] + bih0 + bhh0 -------------
  for (int half = 0; half < 2; ++half) {
    const float* W   = half ? p.dWih0 : p.eWih0;
    const float* bi  = half ? p.dbih0 : p.ebih0;
    const float* bh  = half ? p.dbhh0 : p.ebhh0;
    const float* emb = half ? p.emb_tgt : p.emb_src;
    float* gih       = half ? p.gihD : p.gihE;
    for (int pp = 0; pp < 4; ++pp) {
      int pair = pp * NTHR + tid;          // (row-in-wg, t): 16 rows x 64 t per wg
      int row  = wg * 16 + (pair >> 6);
      int t    = pair & 63;
      int tok  = half ? (t ? p.tgt[t-1] : 0) : p.src[t];   // BOS = 0
      const float4* xr = (const float4*)(emb + (size_t)tok * NH);
      const float4* wr = (const float4*)(W + (size_t)row * NH);
      float a0=0.f,a1=0.f,a2=0.f,a3=0.f;
      #pragma unroll 4
      for (int k = 0; k < NH/4; ++k) {
        float4 x = xr[k], w = wr[k];
        a0 = fmaf(x.x,w.x,a0); a1 = fmaf(x.y,w.y,a1);
        a2 = fmaf(x.z,w.z,a2); a3 = fmaf(x.w,w.w,a3);
      }
      gih[t*NG + row] = (a0+a1)+(a2+a3) + bi[row] + bh[row];
    }
  }

  // ------------- encoder recurrent weights -> registers -------------
  float w0[64], wiA[64], whA[64];
  load_row64(p.eWhh0 + (size_t)rowg*NH, w0,  c16);
  load_row64(p.eWih1 + (size_t)rowg*NH, wiA, c16);
  load_row64(p.eWhh1 + (size_t)rowg*NH, whA, c16);
  float b1 = p.ebih1[rowg] + p.ebhh1[rowg];

  float c0s = 0.f, c1s = 0.f;   // cell states for unit u (lane-replicated)

  gbar<true>(p, ++rnd);         // gih (normal stores) ready -> full fence

  // ---- Phase B: 65 rounds/phase; round r = L0(t=r) || L1(t=r-1) ----
  for (int phase = 0; phase < 2; ++phase) {
    const float* gih = phase ? p.gihD : p.gihE;
    for (int r = 0; r <= NT; ++r) {
      // issue the (h-independent) gih load first: LLC latency hides under staging
      float gval = (r < NT) ? gih[r*NG + rowg] : 0.f;
      // stage h0_{r-1} (buf (r&1)^1) and h1_{r-2} (buf r&1) into LDS via
      // agent-scope loads (sc0 sc1: read LLC, skip stale L1/L2). Lane-stride-1
      // -> 1KB contiguous per instruction per wg; LDS write stride-1 (free).
      {
        const float* hb0 = p.h0b + (((r&1)^1) << 10);
        const float* hb1 = p.h1b + ((r&1) << 10);
        #pragma unroll
        for (int j = 0; j < 4; ++j) {
          hst0[j*256 + tid] = __hip_atomic_load(hb0 + j*256 + tid,
                                 __ATOMIC_RELAXED, __HIP_MEMORY_SCOPE_AGENT);
          hst1[j*256 + tid] = __hip_atomic_load(hb1 + j*256 + tid,
                                 __ATOMIC_RELAXED, __HIP_MEMORY_SCOPE_AGENT);
        }
      }
      __syncthreads();

      float h0s[64];
      load_row64(hst0, h0s, c16);

      if (r < NT) {           // layer 0, t = r
        float a0=0.f,a1=0.f,a2=0.f,a3=0.f;
        #pragma unroll
        for (int i = 0; i < 16; ++i) {
          a0 = fmaf(w0[4*i+0], h0s[4*i+0], a0);
          a1 = fmaf(w0[4*i+1], h0s[4*i+1], a1);
          a2 = fmaf(w0[4*i+2], h0s[4*i+2], a2);
          a3 = fmaf(w0[4*i+3], h0s[4*i+3], a3);
        }
        float acc = (a0+a1)+(a2+a3);
        #pragma unroll
        for (int m = 1; m <= 8; m <<= 1) acc += __shfl_xor(acc, m, 64);
        acc += gval;
        float p0 = __shfl(acc, c16,      64);   // gate i
        float p1 = __shfl(acc, c16 + 16, 64);   // gate f
        float p2 = __shfl(acc, c16 + 32, 64);   // gate g
        float p3 = __shfl(acc, c16 + 48, 64);   // gate o
        c0s = sigf(p1) * c0s + sigf(p0) * tanhf(p2);
        float h0new = sigf(p3) * tanhf(c0s);
        if (l == 0)
          __hip_atomic_store(&p.h0b[((r&1) << 10) + u], h0new,
                             __ATOMIC_RELAXED, __HIP_MEMORY_SCOPE_AGENT);
      }

      if (r >= 1) {           // layer 1, t = r-1 (uses h0_{r-1}=h0s, h1_{r-2})
        float h1s[64];
        load_row64(hst1, h1s, c16);
        float a0=0.f,a1=0.f,a2=0.f,a3=0.f;
        #pragma unroll
        for (int i = 0; i < 16; ++i) {
          a0 = fmaf(wiA[4*i+0], h0s[4*i+0], a0);
          a1 = fmaf(wiA[4*i+1], h0s[4*i+1], a1);
          a2 = fmaf(wiA[4*i+2], h0s[4*i+2], a2);
          a3 = fmaf(wiA[4*i+3], h0s[4*i+3], a3);
        }
        #pragma unroll
        for (int i = 0; i < 16; ++i) {
          a0 = fmaf(whA[4*i+0], h1s[4*i+0], a0);
          a1 = fmaf(whA[4*i+1], h1s[4*i+1], a1);
          a2 = fmaf(whA[4*i+2], h1s[4*i+2], a2);
          a3 = fmaf(whA[4*i+3], h1s[4*i+3], a3);
        }
        float acc = (a0+a1)+(a2+a3);
        #pragma unroll
        for (int m = 1; m <= 8; m <<= 1) acc += __shfl_xor(acc, m, 64);
        acc += b1;
        float p0 = __shfl(acc, c16,      64);
        float p1 = __shfl(acc, c16 + 16, 64);
        float p2 = __shfl(acc, c16 + 32, 64);
        float p3 = __shfl(acc, c16 + 48, 64);
        c1s = sigf(p1) * c1s + sigf(p0) * tanhf(p2);
        float h1new = sigf(p3) * tanhf(c1s);
        if (l == 0) {
          __hip_atomic_store(&p.h1b[(((r&1)^1) << 10) + u], h1new,
                             __ATOMIC_RELAXED, __HIP_MEMORY_SCOPE_AGENT);
          if (phase) {
            // transposed-quad layout [k/4][t][4]: elem (k=u, t=r-1).
            // normal store: covered by the final FENCED barrier before Phase C.
            int tt = r - 1;
            p.dechT[(u >> 2)*256 + tt*4 + (u & 3)] = fmaxf(h1new, 0.f);
          }
        }
      }
      // steady-state: fence-free barrier. Last round (decoder r==NT): full
      // fence so dechT's normal stores are LLC-visible for Phase C.
      if (phase == 1 && r == NT) gbar<true>(p, ++rnd);
      else                       gbar<false>(p, ++rnd);
    }
    if (phase == 0) {   // swap to decoder weights (carry stays in h bufs / c regs)
      load_row64(p.dWhh0 + (size_t)rowg*NH, w0,  c16);
      load_row64(p.dWih1 + (size_t)rowg*NH, wiA, c16);
      load_row64(p.dWhh1 + (size_t)rowg*NH, whA, c16);
      b1 = p.dbih1[rowg] + p.dbhh1[rowg];
    }
  }

  // ---- Phase C: logits[t][v] = relu(dec_h)[t] . outW[v] + outb[v] ----
  // 4 chunks x 32 outW rows in LDS (128 KB); wave vs owns 8 rows; x loads are
  // one coalesced dwordx4 per 4-k block via the transposed dechT layout.
  const int t  = tid & 63;
  const int vs = tid >> 6;
  const int vbase = wg * 125;              // 256 wgs x 125 rows = 32000
  const float4* xT4 = (const float4*)p.dechT;    // [256][64] float4
  float4* Wl4 = (float4*)Wl;
  const float4* oW4 = (const float4*)p.outW;
  for (int ch = 0; ch < 4; ++ch) {
    int rbase = ch * 32;
    __syncthreads();
    #pragma unroll
    for (int i = 0; i < 32; ++i) {         // stage 32 rows, 4KB coalesced each
      int vr = rbase + i; if (vr > 124) vr = 124;
      Wl4[i*256 + tid] = oW4[(size_t)(vbase + vr)*256 + tid];
    }
    __syncthreads();
    float ac[32];
    #pragma unroll
    for (int i = 0; i < 32; ++i) ac[i] = 0.f;
    const float4* q0 = (const float4*)(Wl + (8*vs+0)*NH);
    const float4* q1 = (const float4*)(Wl + (8*vs+1)*NH);
    const float4* q2 = (const float4*)(Wl + (8*vs+2)*NH);
    const float4* q3 = (const float4*)(Wl + (8*vs+3)*NH);
    const float4* q4 = (const float4*)(Wl + (8*vs+4)*NH);
    const float4* q5 = (const float4*)(Wl + (8*vs+5)*NH);
    const float4* q6 = (const float4*)(Wl + (8*vs+6)*NH);
    const float4* q7 = (const float4*)(Wl + (8*vs+7)*NH);
    #pragma unroll 4
    for (int kb = 0; kb < 256; ++kb) {     // kb = k/4
      float4 x = xT4[kb*64 + t];           // coalesced: 64 lanes = 1KB contiguous
      float4 w;
      w = q0[kb]; ac[ 0]=fmaf(x.x,w.x,ac[ 0]); ac[ 1]=fmaf(x.y,w.y,ac[ 1]); ac[ 2]=fmaf(x.z,w.z,ac[ 2]); ac[ 3]=fmaf(x.w,w.w,ac[ 3]);
      w = q1[kb]; ac[ 4]=fmaf(x.x,w.x,ac[ 4]); ac[ 5]=fmaf(x.y,w.y,ac[ 5]); ac[ 6]=fmaf(x.z,w.z,ac[ 6]); ac[ 7]=fmaf(x.w,w.w,ac[ 7]);
      w = q2[kb]; ac[ 8]=fmaf(x.x,w.x,ac[ 8]); ac[ 9]=fmaf(x.y,w.y,ac[ 9]); ac[10]=fmaf(x.z,w.z,ac[10]); ac[11]=fmaf(x.w,w.w,ac[11]);
      w = q3[kb]; ac[12]=fmaf(x.x,w.x,ac[12]); ac[13]=fmaf(x.y,w.y,ac[13]); ac[14]=fmaf(x.z,w.z,ac[14]); ac[15]=fmaf(x.w,w.w,ac[15]);
      w = q4[kb]; ac[16]=fmaf(x.x,w.x,ac[16]); ac[17]=fmaf(x.y,w.y,ac[17]); ac[18]=fmaf(x.z,w.z,ac[18]); ac[19]=fmaf(x.w,w.w,ac[19]);
      w = q5[kb]; ac[20]=fmaf(x.x,w.x,ac[20]); ac[21]=fmaf(x.y,w.y,ac[21]); ac[22]=fmaf(x.z,w.z,ac[22]); ac[23]=fmaf(x.w,w.w,ac[23]);
      w = q6[kb]; ac[24]=fmaf(x.x,w.x,ac[24]); ac[25]=fmaf(x.y,w.y,ac[25]); ac[26]=fmaf(x.z,w.z,ac[26]); ac[27]=fmaf(x.w,w.w,ac[27]);
      w = q7[kb]; ac[28]=fmaf(x.x,w.x,ac[28]); ac[29]=fmaf(x.y,w.y,ac[29]); ac[30]=fmaf(x.z,w.z,ac[30]); ac[31]=fmaf(x.w,w.w,ac[31]);
    }
    #pragma unroll
    for (int j = 0; j < 8; ++j) {
      int cr = rbase + 8*vs + j;
      if (cr < 125) {
        int v = vbase + cr;
        float s = (ac[4*j]+ac[4*j+1])+(ac[4*j+2]+ac[4*j+3]);
        p.out[(size_t)t*NV + v] = s + p.outb[v];
      }
    }
  }
}

extern "C" void kernel_launch(void* const* d_in, const int* in_sizes, int n_in,
                              void* d_out, int out_size, void* d_ws, size_t ws_size,
                              hipStream_t stream) {
  (void)in_sizes; (void)n_in; (void)out_size; (void)ws_size;
  SeqParams P;
  P.src     = (const int*)d_in[0];
  P.tgt     = (const int*)d_in[1];
  P.emb_src = (const float*)d_in[2];
  P.emb_tgt = (const float*)d_in[3];
  P.eWih0 = (const float*)d_in[4];  P.eWhh0 = (const float*)d_in[5];
  P.ebih0 = (const float*)d_in[6];  P.ebhh0 = (const float*)d_in[7];
  P.eWih1 = (const float*)d_in[8];  P.eWhh1 = (const float*)d_in[9];
  P.ebih1 = (const float*)d_in[10]; P.ebhh1 = (const float*)d_in[11];
  P.dWih0 = (const float*)d_in[12]; P.dWhh0 = (const float*)d_in[13];
  P.dbih0 = (const float*)d_in[14]; P.dbhh0 = (const float*)d_in[15];
  P.dWih1 = (const float*)d_in[16]; P.dWhh1 = (const float*)d_in[17];
  P.dbih1 = (const float*)d_in[18]; P.dbhh1 = (const float*)d_in[19];
  P.outW  = (const float*)d_in[20];
  P.outb  = (const float*)d_in[21];
  P.out   = (float*)d_out;

  char* ws = (char*)d_ws;
  P.cnt   = (unsigned*)ws;                              // @0 (own line)
  P.flag  = (unsigned*)(ws + 256);                      // own line
  P.gcnt  = (unsigned*)(ws + 512);                      // 8 counters, 128B apart
  P.h0b   = (float*)(ws + 2048);                        // [2][1024]
  P.h1b   = (float*)(ws + 10240);                       // [2][1024]
  P.gihE  = (float*)(ws + 18432);                       // [64][4096]
  P.gihD  = (float*)(ws + 18432 + 1048576);             // [64][4096]
  P.dechT = (float*)(ws + 18432 + 2097152);             // [256][64][4] transposed
  // zero: cnt/flag/gcnt + both h double-buffers (carry-in = 0)
  hipMemsetAsync(d_ws, 0, 18432, stream);

  seq2seq_kernel<<<dim3(NWG), dim3(NTHR), 0, stream>>>(P);
}